// Round 9
// baseline (720.563 us; speedup 1.0000x reference)
//
#include <hip/hip_runtime.h>
#include <hip/hip_bf16.h>
#include <math.h>

#define NN 50000
#define EE 400000
#define D_IN 256
#define D_H 64
#define N_CLS 50

typedef __attribute__((ext_vector_type(8))) short bfrag;   // 8 bf16 (4 VGPR)
typedef __attribute__((ext_vector_type(4))) float ffrag;   // MFMA C/D
typedef __attribute__((ext_vector_type(8))) unsigned short u16x8_t;
typedef __attribute__((ext_vector_type(4))) unsigned short u16x4_t;

__device__ __forceinline__ unsigned short f2bf(float v) {
    unsigned int u = __float_as_uint(v);
    unsigned int r = (u + 0x7fffu + ((u >> 16) & 1u)) >> 16;   // RNE
    return (unsigned short)r;
}
__device__ __forceinline__ float bf2f(unsigned short b) {
    return __uint_as_float(((unsigned int)b) << 16);
}

// ---------------------------------------------------------------------------
// CSR construction — parallel 3-phase scan (verified r7)
// ---------------------------------------------------------------------------
__global__ void zero_k(int* p, int n) {
    int i = blockIdx.x * blockDim.x + threadIdx.x;
    if (i < n) p[i] = 0;
}

__global__ void count_k(const int* __restrict__ ei, int* __restrict__ cnt, int E, int N) {
    int i = blockIdx.x * blockDim.x + threadIdx.x;
    if (i >= E + N) return;
    int dst = (i < E) ? ei[E + i] : (i - E);
    atomicAdd(&cnt[dst], 1);
}

__global__ __launch_bounds__(1024) void scan1_k(const int* __restrict__ counts,
                                                int* __restrict__ excl,
                                                int* __restrict__ bsum, int n) {
    __shared__ int wsum[16];
    int t = threadIdx.x;
    int lane = t & 63, wid = t >> 6;
    int idx = blockIdx.x * 1024 + t;
    int v = (idx < n) ? counts[idx] : 0;
    int incl = v;
    #pragma unroll
    for (int off = 1; off < 64; off <<= 1) {
        int x = __shfl_up(incl, off);
        if (lane >= off) incl += x;
    }
    if (lane == 63) wsum[wid] = incl;
    __syncthreads();
    if (wid == 0) {
        int ws = (lane < 16) ? wsum[lane] : 0;
        int wincl = ws;
        #pragma unroll
        for (int off = 1; off < 16; off <<= 1) {
            int x = __shfl_up(wincl, off);
            if (lane >= off) wincl += x;
        }
        if (lane < 16) wsum[lane] = wincl - ws;   // exclusive wave prefix
    }
    __syncthreads();
    if (idx < n) excl[idx] = wsum[wid] + (incl - v);
    if (t == 1023) bsum[blockIdx.x] = wsum[15] + incl;
}

__global__ void scan2_k(int* __restrict__ bsum, int nb) {
    int lane = threadIdx.x & 63;
    int v = (lane < nb) ? bsum[lane] : 0;
    int incl = v;
    #pragma unroll
    for (int off = 1; off < 64; off <<= 1) {
        int x = __shfl_up(incl, off);
        if (lane >= off) incl += x;
    }
    if (lane < nb) bsum[lane] = incl - v;
}

__global__ void scan3_k(const int* __restrict__ excl, const int* __restrict__ bsum,
                        int* __restrict__ rowptr, int n, int total) {
    int i = blockIdx.x * 256 + threadIdx.x;
    if (i < n) rowptr[i] = excl[i] + bsum[i >> 10];
    if (i == 0) rowptr[n] = total;
}

__global__ void fill_k(const int* __restrict__ ei, const int* __restrict__ rowptr,
                       int* __restrict__ cursor, int* __restrict__ csr, int E, int N) {
    int i = blockIdx.x * blockDim.x + threadIdx.x;
    if (i >= E + N) return;
    int s, d;
    if (i < E) { s = ei[i]; d = ei[E + i]; }
    else       { s = i - E; d = i - E; }
    int pos = atomicAdd(&cursor[d], 1);
    csr[rowptr[d] + pos] = s;
}

// ---------------------------------------------------------------------------
// Extended-K conversions: A -> [hi | lo | hi], B[K][N] -> BT_ext[N][3K] =
// [hi | hi | lo]. Sum over KE reproduces hi*hi + lo*hi + hi*lo exactly.
// ---------------------------------------------------------------------------
__global__ void cvt_a3_k(const float* __restrict__ a, unsigned short* __restrict__ ext,
                         int M, int K) {
    int i = blockIdx.x * 256 + threadIdx.x;
    if (i >= M * K) return;
    int r = i / K, c = i - r * K;
    float v = a[i];
    unsigned short h = f2bf(v);
    unsigned short l = f2bf(v - bf2f(h));
    size_t b = (size_t)r * (3 * K) + c;
    ext[b] = h; ext[b + K] = l; ext[b + 2 * K] = h;
}

__global__ void cvt_bt3_k(const float* __restrict__ B, unsigned short* __restrict__ ext,
                          int K, int N) {
    int i = blockIdx.x * 256 + threadIdx.x;
    if (i >= K * N) return;
    int k = i / N, n = i - k * N;
    float v = B[i];
    unsigned short h = f2bf(v);
    unsigned short l = f2bf(v - bf2f(h));
    size_t b = (size_t)n * (3 * K) + k;
    ext[b] = h; ext[b + K] = h; ext[b + 2 * K] = l;
}

// BN folding: scale = g*rsqrt(v+eps); shift = (bias - m)*scale + b
__global__ void bnprep_k(const float* __restrict__ g, const float* __restrict__ b,
                         const float* __restrict__ m, const float* __restrict__ v,
                         const float* __restrict__ bias,
                         float* __restrict__ scale, float* __restrict__ shift) {
    int t = threadIdx.x;
    if (t < 64) {
        float sc = g[t] * rsqrtf(v[t] + 1e-5f);
        scale[t] = sc;
        shift[t] = (bias[t] - m[t]) * sc + b[t];
    }
}

// ---------------------------------------------------------------------------
// DIRECT-LOAD ext-K MFMA GEMM — no LDS, no barriers. Wave owns a 64x64 tile;
// A/B fragments loaded straight from global as coalesced 16B/lane dwordx4
// (wave = 16 rows x 64B contiguous), register double-buffered across K.
// MW*NW waves; block covers MW*64 rows x NW*64 cols (NW*64 >= N). A rows
// shared by same-mtile waves via L1; B (<=786KB) is L2-resident.
// Epilogues: fp32 / bf16 / split-ext C, bias+ReLU, fused attention scores.
// ---------------------------------------------------------------------------
template <int MW, int NW>
__global__ __launch_bounds__(MW * NW * 64) void gemm_direct_k(
    const unsigned short* __restrict__ Aext,   // [M][KE]
    const unsigned short* __restrict__ BTe,    // [N][KE]
    float* __restrict__ Cf, unsigned short* __restrict__ Chi,
    unsigned short* __restrict__ Cext,         // [M][3N] split ext out
    int M, int N, int KE,
    const float* __restrict__ bias, int do_relu,
    const float* __restrict__ att_s, const float* __restrict__ att_d,
    float* __restrict__ asb, float* __restrict__ adb) {
    const int tid = threadIdx.x;
    const int lane = tid & 63, w = tid >> 6;
    const int mtile = w / NW, ntile = w % NW;
    const int c16 = lane & 15, kq = lane >> 4;
    const int m0 = blockIdx.x * (MW * 64) + mtile * 64;
    const int n0 = ntile * 64;

    // per-fragment global pointers (advance +32 shorts per K-iter)
    const unsigned short* aptr[4];
    const unsigned short* bptr[4];
    #pragma unroll
    for (int t = 0; t < 4; t++) {
        int row = min(m0 + t * 16 + c16, M - 1);
        aptr[t] = Aext + (size_t)row * KE + kq * 8;
        int col = min(n0 + t * 16 + c16, N - 1);
        bptr[t] = BTe + (size_t)col * KE + kq * 8;
    }

    ffrag acc[4][4] = {};
    bfrag a[4], b[4];
    #pragma unroll
    for (int t = 0; t < 4; t++) {
        a[t] = *(const bfrag*)aptr[t]; aptr[t] += 32;
        b[t] = *(const bfrag*)bptr[t]; bptr[t] += 32;
    }
    for (int k0 = 32; k0 <= KE; k0 += 32) {
        bfrag an[4], bn[4];
        if (k0 < KE) {
            #pragma unroll
            for (int t = 0; t < 4; t++) {
                an[t] = *(const bfrag*)aptr[t]; aptr[t] += 32;
                bn[t] = *(const bfrag*)bptr[t]; bptr[t] += 32;
            }
        }
        #pragma unroll
        for (int mt = 0; mt < 4; mt++)
            #pragma unroll
            for (int nt = 0; nt < 4; nt++)
                acc[mt][nt] = __builtin_amdgcn_mfma_f32_16x16x32_bf16(a[mt], b[nt], acc[mt][nt], 0, 0, 0);
        if (k0 < KE) {
            #pragma unroll
            for (int t = 0; t < 4; t++) { a[t] = an[t]; b[t] = bn[t]; }
        }
    }

    // ---- fused attention scores (raw h; GAT layers). ntile == head ----
    if (att_s) {
        int hidx = ntile;
        float s_att[4], d_att[4];
        #pragma unroll
        for (int nt = 0; nt < 4; nt++) {
            s_att[nt] = att_s[hidx * 64 + nt * 16 + c16];
            d_att[nt] = att_d[hidx * 64 + nt * 16 + c16];
        }
        #pragma unroll
        for (int mt = 0; mt < 4; mt++) {
            #pragma unroll
            for (int r = 0; r < 4; r++) {
                int row = m0 + mt * 16 + kq * 4 + r;
                float ps = 0.f, pd = 0.f;
                #pragma unroll
                for (int nt = 0; nt < 4; nt++) {
                    ps = fmaf(acc[mt][nt][r], s_att[nt], ps);
                    pd = fmaf(acc[mt][nt][r], d_att[nt], pd);
                }
                #pragma unroll
                for (int msk = 1; msk < 16; msk <<= 1) {
                    ps += __shfl_xor(ps, msk);
                    pd += __shfl_xor(pd, msk);
                }
                if (c16 == 0 && row < M) {
                    asb[(size_t)row * NW + hidx] = ps;
                    adb[(size_t)row * NW + hidx] = pd;
                }
            }
        }
    }

    // ---- C write ----
    #pragma unroll
    for (int mt = 0; mt < 4; mt++) {
        #pragma unroll
        for (int r = 0; r < 4; r++) {
            int row = m0 + mt * 16 + kq * 4 + r;
            if (row >= M) continue;
            #pragma unroll
            for (int nt = 0; nt < 4; nt++) {
                int col = n0 + nt * 16 + c16;
                if (col >= N) continue;
                float v = acc[mt][nt][r];
                if (bias) v += bias[col];
                if (do_relu) v = fmaxf(v, 0.f);
                if (Cf) Cf[(size_t)row * N + col] = v;
                if (Chi) Chi[(size_t)row * N + col] = f2bf(v);
                if (Cext) {
                    unsigned short hh = f2bf(v);
                    unsigned short ll = f2bf(v - bf2f(hh));
                    size_t b = (size_t)row * (3 * N);
                    Cext[b + col] = hh;
                    Cext[b + N + col] = ll;
                    Cext[b + 2 * N + col] = hh;
                }
            }
        }
    }
}

__device__ __forceinline__ float wave_max_f(float v) {
    #pragma unroll
    for (int off = 32; off; off >>= 1) v = fmaxf(v, __shfl_xor(v, off));
    return v;
}
__device__ __forceinline__ float wave_sum_f(float v) {
    #pragma unroll
    for (int off = 32; off; off >>= 1) v += __shfl_xor(v, off);
    return v;
}

// ---------------------------------------------------------------------------
// Aggregation (verified r5-r8): one wave per node, all heads, bf16 gather.
// Output in split-ext layout [hi | lo | hi] (stride 192).
// ---------------------------------------------------------------------------
template <int H, bool MEAN_BN>
__global__ __launch_bounds__(256) void agg_k(
    const unsigned short* __restrict__ hfeat,   // [N, H*64] bf16
    const float* __restrict__ a_s, const float* __restrict__ a_d,
    const int* __restrict__ rowptr, const int* __restrict__ csr,
    const float* __restrict__ scale,   // MEAN_BN: folded BN scale; else unused
    const float* __restrict__ shift,   // MEAN_BN: folded BN shift; else bias
    unsigned short* __restrict__ outext, int N) {
    constexpr int OUT = H * 64;
    constexpr int F = H;
    constexpr int G = 64 / H;
    __shared__ float alpha_s[4][H][65];
    const int wv = threadIdx.x >> 6;
    const int lane = threadIdx.x & 63;
    const int node = blockIdx.x * 4 + wv;
    if (node >= N) return;        // no __syncthreads in this kernel — safe

    const int row = rowptr[node];
    const int deg = rowptr[node + 1] - row;
    const int hl = lane / G;

    float adn[H];
    #pragma unroll
    for (int h = 0; h < H; h++) adn[h] = a_d[(size_t)node * H + h];

    float acc[F] = {};

    if (deg <= 64) {
        int s = 0;
        float e[H];
        #pragma unroll
        for (int h = 0; h < H; h++) e[h] = -INFINITY;
        if (lane < deg) {
            s = csr[row + lane];
            const float* ap = a_s + (size_t)s * H;
            if constexpr (H >= 4) {
                #pragma unroll
                for (int h4 = 0; h4 < H; h4 += 4) {
                    float4 av = *(const float4*)(ap + h4);
                    e[h4 + 0] = av.x + adn[h4 + 0];
                    e[h4 + 1] = av.y + adn[h4 + 1];
                    e[h4 + 2] = av.z + adn[h4 + 2];
                    e[h4 + 3] = av.w + adn[h4 + 3];
                }
            } else {
                e[0] = ap[0] + adn[0];
            }
            #pragma unroll
            for (int h = 0; h < H; h++) e[h] = e[h] > 0.f ? e[h] : 0.2f * e[h];
        }
        float m[H], p[H], inv[H];
        #pragma unroll
        for (int h = 0; h < H; h++) m[h] = wave_max_f(e[h]);
        #pragma unroll
        for (int h = 0; h < H; h++) p[h] = (lane < deg) ? __expf(e[h] - m[h]) : 0.f;
        #pragma unroll
        for (int h = 0; h < H; h++) inv[h] = 1.f / (wave_sum_f(p[h]) + 1e-16f);
        if (lane < deg) {
            #pragma unroll
            for (int h = 0; h < H; h++) alpha_s[wv][h][lane] = p[h] * inv[h];
        }
        asm volatile("s_waitcnt lgkmcnt(0)" ::: "memory");
        for (int jj = 0; jj < deg; jj++) {
            int ss = __builtin_amdgcn_readlane(s, jj);
            float al = alpha_s[wv][hl][jj];
            const unsigned short* rp = hfeat + (size_t)ss * OUT + lane * F;
            if constexpr (F == 8) {
                u16x8_t u = *(const u16x8_t*)rp;
                #pragma unroll
                for (int i = 0; i < 8; i++) acc[i] = fmaf(al, bf2f(u[i]), acc[i]);
            } else if constexpr (F == 4) {
                u16x4_t u = *(const u16x4_t*)rp;
                #pragma unroll
                for (int i = 0; i < 4; i++) acc[i] = fmaf(al, bf2f(u[i]), acc[i]);
            } else {
                acc[0] = fmaf(al, bf2f(rp[0]), acc[0]);
            }
        }
    } else {
        float m[H];
        #pragma unroll
        for (int h = 0; h < H; h++) m[h] = -INFINITY;
        for (int c0 = 0; c0 < deg; c0 += 64) {
            int j = c0 + lane;
            if (j < deg) {
                int s2 = csr[row + j];
                #pragma unroll
                for (int h = 0; h < H; h++) {
                    float e = a_s[(size_t)s2 * H + h] + adn[h];
                    e = e > 0.f ? e : 0.2f * e;
                    m[h] = fmaxf(m[h], e);
                }
            }
        }
        #pragma unroll
        for (int h = 0; h < H; h++) m[h] = wave_max_f(m[h]);
        float dsum[H] = {};
        for (int c0 = 0; c0 < deg; c0 += 64) {
            int j = c0 + lane;
            if (j < deg) {
                int s2 = csr[row + j];
                #pragma unroll
                for (int h = 0; h < H; h++) {
                    float e = a_s[(size_t)s2 * H + h] + adn[h];
                    e = e > 0.f ? e : 0.2f * e;
                    dsum[h] += __expf(e - m[h]);
                }
            }
        }
        float inv[H];
        #pragma unroll
        for (int h = 0; h < H; h++) inv[h] = 1.f / (wave_sum_f(dsum[h]) + 1e-16f);
        for (int c0 = 0; c0 < deg; c0 += 64) {
            int j = c0 + lane;
            int cnt = min(64, deg - c0);
            int s = 0;
            if (j < deg) {
                s = csr[row + j];
                #pragma unroll
                for (int h = 0; h < H; h++) {
                    float e = a_s[(size_t)s * H + h] + adn[h];
                    e = e > 0.f ? e : 0.2f * e;
                    alpha_s[wv][h][lane] = __expf(e - m[h]) * inv[h];
                }
            }
            asm volatile("s_waitcnt lgkmcnt(0)" ::: "memory");
            for (int jj = 0; jj < cnt; jj++) {
                int ss = __builtin_amdgcn_readlane(s, jj);
                float al = alpha_s[wv][hl][jj];
                const unsigned short* rp = hfeat + (size_t)ss * OUT + lane * F;
                if constexpr (F == 8) {
                    u16x8_t u = *(const u16x8_t*)rp;
                    #pragma unroll
                    for (int i = 0; i < 8; i++) acc[i] = fmaf(al, bf2f(u[i]), acc[i]);
                } else if constexpr (F == 4) {
                    u16x4_t u = *(const u16x4_t*)rp;
                    #pragma unroll
                    for (int i = 0; i < 4; i++) acc[i] = fmaf(al, bf2f(u[i]), acc[i]);
                } else {
                    acc[0] = fmaf(al, bf2f(rp[0]), acc[0]);
                }
            }
            asm volatile("s_waitcnt lgkmcnt(0)" ::: "memory");
        }
    }

    if constexpr (MEAN_BN) {
        #pragma unroll
        for (int i = 0; i < F; i++) {
            #pragma unroll
            for (int msk = G; msk < 64; msk <<= 1)
                acc[i] += __shfl_xor(acc[i], msk);
        }
        if (lane < G) {
            int c0 = lane * F;
            size_t b = (size_t)node * 192;
            #pragma unroll
            for (int i = 0; i < F; i++) {
                float v = fmaf(acc[i] * (1.0f / H), scale[c0 + i], shift[c0 + i]);
                v = fmaxf(v, 0.f);
                unsigned short hh = f2bf(v);
                unsigned short ll = f2bf(v - bf2f(hh));
                outext[b + c0 + i] = hh;
                outext[b + 64 + c0 + i] = ll;
                outext[b + 128 + c0 + i] = hh;
            }
        }
    } else {
        float v = acc[0] + shift[lane];
        unsigned short hh = f2bf(v);
        unsigned short ll = f2bf(v - bf2f(hh));
        size_t b = (size_t)node * 192;
        outext[b + lane] = hh;
        outext[b + 64 + lane] = ll;
        outext[b + 128 + lane] = hh;
    }
}

// ---------------------------------------------------------------------------
// Softmax over N_CLS logits, wave per node.
// ---------------------------------------------------------------------------
__global__ __launch_bounds__(256) void softmax_k(const float* __restrict__ logits,
                                                 float* __restrict__ out, int N) {
    int lane = threadIdx.x & 63;
    int n = (blockIdx.x * blockDim.x + threadIdx.x) >> 6;
    if (n >= N) return;
    float lg = (lane < N_CLS) ? logits[(size_t)n * N_CLS + lane] : -INFINITY;
    float m = wave_max_f(lg);
    float p = (lane < N_CLS) ? __expf(lg - m) : 0.f;
    float s = wave_sum_f(p);
    if (lane < N_CLS) out[(size_t)n * N_CLS + lane] = p / s;
}

// ---------------------------------------------------------------------------
extern "C" void kernel_launch(void* const* d_in, const int* in_sizes, int n_in,
                              void* d_out, int out_size, void* d_ws, size_t ws_size,
                              hipStream_t stream) {
    const int N = NN, E = EE, E2 = EE + NN;
    const float* x    = (const float*)d_in[0];
    const int*   ei   = (const int*)d_in[1];
    const float* W1   = (const float*)d_in[2];
    const float* as1  = (const float*)d_in[3];
    const float* ad1  = (const float*)d_in[4];
    const float* b1   = (const float*)d_in[5];
    const float* W2   = (const float*)d_in[6];
    const float* as2  = (const float*)d_in[7];
    const float* ad2  = (const float*)d_in[8];
    const float* b2   = (const float*)d_in[9];
    const float* W3   = (const float*)d_in[10];
    const float* as3  = (const float*)d_in[11];
    const float* ad3  = (const float*)d_in[12];
    const float* b3   = (const float*)d_in[13];
    const float* bn1g = (const float*)d_in[14];
    const float* bn1b = (const float*)d_in[15];
    const float* bn1m = (const float*)d_in[16];
    const float* bn1v = (const float*)d_in[17];
    const float* bn2g = (const float*)d_in[18];
    const float* bn2b = (const float*)d_in[19];
    const float* bn2m = (const float*)d_in[20];
    const float* bn2v = (const float*)d_in[21];
    const float* cW1  = (const float*)d_in[22];
    const float* cb1  = (const float*)d_in[23];
    const float* cW2  = (const float*)d_in[24];
    const float* cb2  = (const float*)d_in[25];
    float* out = (float*)d_out;

    char* ws = (char*)d_ws;
    size_t off = 0;
    auto alloc = [&](size_t bytes) {
        void* p = ws + off;
        off = (off + bytes + 255) & ~(size_t)255;
        return p;
    };
    int*   rowptr = (int*)alloc((size_t)(N + 1) * 4);
    int*   cursor = (int*)alloc((size_t)N * 4);
    int*   excl   = (int*)alloc((size_t)N * 4);
    int*   bsum   = (int*)alloc(64 * 4);
    int*   csr    = (int*)alloc((size_t)E2 * 4);
    unsigned short* xext = (unsigned short*)alloc((size_t)N * 768 * 2);   // 76.8 MB
    unsigned short* hbf  = (unsigned short*)alloc((size_t)N * 512 * 2);   // 51.2 MB
    float* asb    = (float*)alloc((size_t)N * 8 * 4);
    float* adb    = (float*)alloc((size_t)N * 8 * 4);
    unsigned short* f1ext = (unsigned short*)alloc((size_t)N * 192 * 2);
    unsigned short* f2ext = (unsigned short*)alloc((size_t)N * 192 * 2);
    unsigned short* wext  = (unsigned short*)alloc((size_t)512 * 768 * 2);
    float* sc1 = (float*)alloc(64 * 4);
    float* sh1 = (float*)alloc(64 * 4);
    float* sc2 = (float*)alloc(64 * 4);
    float* sh2 = (float*)alloc(64 * 4);
    // aliases (stream-ordered, regions free by then):
    unsigned short* f3ext = f2ext;           // f2ext free after L3 gemm
    unsigned short* zext  = f1ext;           // f1ext free after L2 gemm
    float* logits = (float*)xext;            // xext free after L1 gemm

    const int NB = (N + 1023) / 1024;        // 49 scan blocks

    // ---- CSR build (parallel scan) + BN fold ----
    zero_k<<<(N + 255) / 256, 256, 0, stream>>>(cursor, N);
    count_k<<<(E2 + 255) / 256, 256, 0, stream>>>(ei, cursor, E, N);
    scan1_k<<<NB, 1024, 0, stream>>>(cursor, excl, bsum, N);
    scan2_k<<<1, 64, 0, stream>>>(bsum, NB);
    scan3_k<<<(N + 255) / 256, 256, 0, stream>>>(excl, bsum, rowptr, N, E2);
    zero_k<<<(N + 255) / 256, 256, 0, stream>>>(cursor, N);
    fill_k<<<(E2 + 255) / 256, 256, 0, stream>>>(ei, rowptr, cursor, csr, E, N);
    bnprep_k<<<1, 64, 0, stream>>>(bn1g, bn1b, bn1m, bn1v, b1, sc1, sh1);
    bnprep_k<<<1, 64, 0, stream>>>(bn2g, bn2b, bn2m, bn2v, b2, sc2, sh2);

    const int AB = (N + 3) / 4;

    // ---- Layer 1: heads=8, in=256 (KE=768; 8 waves 1m x 8n, 64 rows/blk) ----
    cvt_a3_k<<<((size_t)N * 256 + 255) / 256, 256, 0, stream>>>(x, xext, N, 256);
    cvt_bt3_k<<<(256 * 512 + 255) / 256, 256, 0, stream>>>(W1, wext, 256, 512);
    gemm_direct_k<1, 8><<<(N + 63) / 64, 512, 0, stream>>>(xext, wext, nullptr, hbf, nullptr,
        N, 512, 768, nullptr, 0, as1, ad1, asb, adb);
    agg_k<8, true><<<AB, 256, 0, stream>>>(hbf, asb, adb, rowptr, csr, sc1, sh1, f1ext, N);

    // ---- Layer 2: heads=4, in=64 (KE=192; 4 waves 1m x 4n, 64 rows/blk) ----
    cvt_bt3_k<<<(64 * 256 + 255) / 256, 256, 0, stream>>>(W2, wext, 64, 256);
    gemm_direct_k<1, 4><<<(N + 63) / 64, 256, 0, stream>>>(f1ext, wext, nullptr, hbf, nullptr,
        N, 256, 192, nullptr, 0, as2, ad2, asb, adb);
    agg_k<4, true><<<AB, 256, 0, stream>>>(hbf, asb, adb, rowptr, csr, sc2, sh2, f2ext, N);

    // ---- Layer 3: heads=1, in=64, concat (KE=192; 4 waves 4m x 1n, 256 rows) ----
    cvt_bt3_k<<<(64 * 64 + 255) / 256, 256, 0, stream>>>(W3, wext, 64, 64);
    gemm_direct_k<4, 1><<<(N + 255) / 256, 256, 0, stream>>>(f2ext, wext, nullptr, hbf, nullptr,
        N, 64, 192, nullptr, 0, as3, ad3, asb, adb);
    agg_k<1, false><<<AB, 256, 0, stream>>>(hbf, asb, adb, rowptr, csr, nullptr, b3, f3ext, N);

    // ---- Classifier: z = relu(f3@cW1+cb1) (ext out); logits; softmax ----
    cvt_bt3_k<<<(64 * 64 + 255) / 256, 256, 0, stream>>>(cW1, wext, 64, 64);
    gemm_direct_k<4, 1><<<(N + 255) / 256, 256, 0, stream>>>(f3ext, wext, nullptr, nullptr, zext,
        N, 64, 192, cb1, 1, nullptr, nullptr, nullptr, nullptr);
    cvt_bt3_k<<<(64 * N_CLS + 255) / 256, 256, 0, stream>>>(cW2, wext, 64, N_CLS);
    gemm_direct_k<4, 1><<<(N + 255) / 256, 256, 0, stream>>>(zext, wext, logits, nullptr, nullptr,
        N, N_CLS, 192, cb2, 0, nullptr, nullptr, nullptr, nullptr);
    softmax_k<<<(N + 3) / 4, 256, 0, stream>>>(logits, out, N);
}

// Round 10
// 533.206 us; speedup vs baseline: 1.3514x; 1.3514x over previous
//
#include <hip/hip_runtime.h>
#include <hip/hip_bf16.h>
#include <math.h>

#define NN 50000
#define EE 400000
#define D_IN 256
#define D_H 64
#define N_CLS 50

typedef __attribute__((ext_vector_type(8))) short bfrag;   // 8 bf16 (4 VGPR)
typedef __attribute__((ext_vector_type(4))) float ffrag;   // MFMA C/D
typedef __attribute__((ext_vector_type(8))) unsigned short u16x8_t;
typedef __attribute__((ext_vector_type(4))) unsigned short u16x4_t;

__device__ __forceinline__ unsigned short f2bf(float v) {
    unsigned int u = __float_as_uint(v);
    unsigned int r = (u + 0x7fffu + ((u >> 16) & 1u)) >> 16;   // RNE
    return (unsigned short)r;
}
__device__ __forceinline__ float bf2f(unsigned short b) {
    return __uint_as_float(((unsigned int)b) << 16);
}

// XOR sub-chunk swizzle (r7-verified: 0 bank conflicts). row stride 32 shorts
// (64B, unpadded); q = 8-short chunk index 0..3. 16B-aligned offsets.
__device__ __forceinline__ int swz(int row, int q) {
    return row * 32 + ((q ^ ((row >> 1) & 3)) << 3);
}

// ---------------------------------------------------------------------------
// CSR construction — parallel 3-phase scan (verified r7)
// ---------------------------------------------------------------------------
__global__ void zero_k(int* p, int n) {
    int i = blockIdx.x * blockDim.x + threadIdx.x;
    if (i < n) p[i] = 0;
}

__global__ void count_k(const int* __restrict__ ei, int* __restrict__ cnt, int E, int N) {
    int i = blockIdx.x * blockDim.x + threadIdx.x;
    if (i >= E + N) return;
    int dst = (i < E) ? ei[E + i] : (i - E);
    atomicAdd(&cnt[dst], 1);
}

__global__ __launch_bounds__(1024) void scan1_k(const int* __restrict__ counts,
                                                int* __restrict__ excl,
                                                int* __restrict__ bsum, int n) {
    __shared__ int wsum[16];
    int t = threadIdx.x;
    int lane = t & 63, wid = t >> 6;
    int idx = blockIdx.x * 1024 + t;
    int v = (idx < n) ? counts[idx] : 0;
    int incl = v;
    #pragma unroll
    for (int off = 1; off < 64; off <<= 1) {
        int x = __shfl_up(incl, off);
        if (lane >= off) incl += x;
    }
    if (lane == 63) wsum[wid] = incl;
    __syncthreads();
    if (wid == 0) {
        int ws = (lane < 16) ? wsum[lane] : 0;
        int wincl = ws;
        #pragma unroll
        for (int off = 1; off < 16; off <<= 1) {
            int x = __shfl_up(wincl, off);
            if (lane >= off) wincl += x;
        }
        if (lane < 16) wsum[lane] = wincl - ws;   // exclusive wave prefix
    }
    __syncthreads();
    if (idx < n) excl[idx] = wsum[wid] + (incl - v);
    if (t == 1023) bsum[blockIdx.x] = wsum[15] + incl;
}

__global__ void scan2_k(int* __restrict__ bsum, int nb) {
    int lane = threadIdx.x & 63;
    int v = (lane < nb) ? bsum[lane] : 0;
    int incl = v;
    #pragma unroll
    for (int off = 1; off < 64; off <<= 1) {
        int x = __shfl_up(incl, off);
        if (lane >= off) incl += x;
    }
    if (lane < nb) bsum[lane] = incl - v;
}

__global__ void scan3_k(const int* __restrict__ excl, const int* __restrict__ bsum,
                        int* __restrict__ rowptr, int n, int total) {
    int i = blockIdx.x * 256 + threadIdx.x;
    if (i < n) rowptr[i] = excl[i] + bsum[i >> 10];
    if (i == 0) rowptr[n] = total;
}

__global__ void fill_k(const int* __restrict__ ei, const int* __restrict__ rowptr,
                       int* __restrict__ cursor, int* __restrict__ csr, int E, int N) {
    int i = blockIdx.x * blockDim.x + threadIdx.x;
    if (i >= E + N) return;
    int s, d;
    if (i < E) { s = ei[i]; d = ei[E + i]; }
    else       { s = i - E; d = i - E; }
    int pos = atomicAdd(&cursor[d], 1);
    csr[rowptr[d] + pos] = s;
}

// ---------------------------------------------------------------------------
// Split-bf16 conversion kernels (x and weights)
// ---------------------------------------------------------------------------
__global__ void cvt_a_k(const float* __restrict__ a, unsigned short* __restrict__ hi,
                        unsigned short* __restrict__ lo, int n) {
    int i = blockIdx.x * 256 + threadIdx.x;
    if (i >= n) return;
    float v = a[i];
    unsigned short h = f2bf(v);
    hi[i] = h;
    lo[i] = f2bf(v - bf2f(h));
}

__global__ void cvt_bt_k(const float* __restrict__ Bsrc, unsigned short* __restrict__ hi,
                         unsigned short* __restrict__ lo, int K, int N) {
    int i = blockIdx.x * 256 + threadIdx.x;
    if (i >= K * N) return;
    int k = i / N, n = i % N;
    float v = Bsrc[i];
    unsigned short h = f2bf(v);
    hi[(size_t)n * K + k] = h;
    lo[(size_t)n * K + k] = f2bf(v - bf2f(h));
}

// BN folding: scale = g*rsqrt(v+eps); shift = (bias - m)*scale + b
__global__ void bnprep_k(const float* __restrict__ g, const float* __restrict__ b,
                         const float* __restrict__ m, const float* __restrict__ v,
                         const float* __restrict__ bias,
                         float* __restrict__ scale, float* __restrict__ shift) {
    int t = threadIdx.x;
    if (t < 64) {
        float sc = g[t] * rsqrtf(v[t] + 1e-5f);
        scale[t] = sc;
        shift[t] = (bias[t] - m[t]) * sc + b[t];
    }
}

// ---------------------------------------------------------------------------
// Split-bf16 MFMA GEMM (r5 structure — best measured — with r7's conflict-free
// XOR-swizzled LDS replacing the padded layout). 64x128 tile, BK=32, 4 waves
// 2x2, wave tile 32x64 = 2x4 MFMAs x 3 split products. Fused epilogues:
// fp32 C / bf16 C (+split lo), bias+ReLU, per-head attention scores.
// ---------------------------------------------------------------------------
__global__ __launch_bounds__(256) void gemm_mfma_k(
    const unsigned short* __restrict__ Ahi, const unsigned short* __restrict__ Alo,
    const unsigned short* __restrict__ BThi, const unsigned short* __restrict__ BTlo,
    float* __restrict__ Cf, unsigned short* __restrict__ Chi, unsigned short* __restrict__ Clo,
    int M, int N, int K,
    const float* __restrict__ bias, int do_relu,
    const float* __restrict__ att_s, const float* __restrict__ att_d,
    float* __restrict__ asb, float* __restrict__ adb, int H) {
    __shared__ unsigned short sAh[64 * 32];
    __shared__ unsigned short sAl[64 * 32];
    __shared__ unsigned short sBh[128 * 32];
    __shared__ unsigned short sBl[128 * 32];
    const int tid = threadIdx.x;
    const int m0 = blockIdx.y * 64;
    const int n0 = blockIdx.x * 128;
    const int lane = tid & 63, w = tid >> 6;
    const int wm = w >> 1, wn = w & 1;
    const int c16 = lane & 15, kq = lane >> 4;
    const int arow = tid >> 2;          // 0..63
    const int q    = tid & 3;           // 8-short chunk 0..3
    const int akc  = q * 8;
    const int aM  = min(m0 + arow, M - 1);
    const int bn0 = min(n0 + arow, N - 1);
    const int bn1 = min(n0 + 64 + arow, N - 1);
    const int wA  = swz(arow, q);
    const int wB0 = swz(arow, q);
    const int wB1 = swz(64 + arow, q);
    ffrag acc[2][4] = {};

    for (int k0 = 0; k0 < K; k0 += 32) {
        bfrag va_h  = *(const bfrag*)(Ahi  + (size_t)aM  * K + k0 + akc);
        bfrag va_l  = *(const bfrag*)(Alo  + (size_t)aM  * K + k0 + akc);
        bfrag vb_h0 = *(const bfrag*)(BThi + (size_t)bn0 * K + k0 + akc);
        bfrag vb_l0 = *(const bfrag*)(BTlo + (size_t)bn0 * K + k0 + akc);
        bfrag vb_h1 = *(const bfrag*)(BThi + (size_t)bn1 * K + k0 + akc);
        bfrag vb_l1 = *(const bfrag*)(BTlo + (size_t)bn1 * K + k0 + akc);
        __syncthreads();
        *(bfrag*)&sAh[wA]  = va_h;
        *(bfrag*)&sAl[wA]  = va_l;
        *(bfrag*)&sBh[wB0] = vb_h0;
        *(bfrag*)&sBl[wB0] = vb_l0;
        *(bfrag*)&sBh[wB1] = vb_h1;
        *(bfrag*)&sBl[wB1] = vb_l1;
        __syncthreads();
        bfrag ah[2], al_[2], bh[4], bl[4];
        #pragma unroll
        for (int mt = 0; mt < 2; mt++) {
            int ra = wm * 32 + mt * 16 + c16;
            ah[mt]  = *(const bfrag*)&sAh[swz(ra, kq)];
            al_[mt] = *(const bfrag*)&sAl[swz(ra, kq)];
        }
        #pragma unroll
        for (int nt = 0; nt < 4; nt++) {
            int rb = wn * 64 + nt * 16 + c16;
            bh[nt] = *(const bfrag*)&sBh[swz(rb, kq)];
            bl[nt] = *(const bfrag*)&sBl[swz(rb, kq)];
        }
        #pragma unroll
        for (int mt = 0; mt < 2; mt++)
            #pragma unroll
            for (int nt = 0; nt < 4; nt++) {
                acc[mt][nt] = __builtin_amdgcn_mfma_f32_16x16x32_bf16(ah[mt],  bh[nt], acc[mt][nt], 0, 0, 0);
                acc[mt][nt] = __builtin_amdgcn_mfma_f32_16x16x32_bf16(ah[mt],  bl[nt], acc[mt][nt], 0, 0, 0);
                acc[mt][nt] = __builtin_amdgcn_mfma_f32_16x16x32_bf16(al_[mt], bh[nt], acc[mt][nt], 0, 0, 0);
            }
    }

    // ---- fused attention scores (raw h, pre-bias/relu; GAT layers only) ----
    if (att_s) {
        int hidx = n0 / 64 + wn;
        if (hidx < H) {
            float s_att[4], d_att[4];
            #pragma unroll
            for (int nt = 0; nt < 4; nt++) {
                s_att[nt] = att_s[hidx * 64 + nt * 16 + c16];
                d_att[nt] = att_d[hidx * 64 + nt * 16 + c16];
            }
            #pragma unroll
            for (int mt = 0; mt < 2; mt++) {
                #pragma unroll
                for (int r = 0; r < 4; r++) {
                    int row = m0 + wm * 32 + mt * 16 + kq * 4 + r;
                    float ps = 0.f, pd = 0.f;
                    #pragma unroll
                    for (int nt = 0; nt < 4; nt++) {
                        ps = fmaf(acc[mt][nt][r], s_att[nt], ps);
                        pd = fmaf(acc[mt][nt][r], d_att[nt], pd);
                    }
                    #pragma unroll
                    for (int msk = 1; msk < 16; msk <<= 1) {
                        ps += __shfl_xor(ps, msk);
                        pd += __shfl_xor(pd, msk);
                    }
                    if (c16 == 0 && row < M) {
                        asb[(size_t)row * H + hidx] = ps;
                        adb[(size_t)row * H + hidx] = pd;
                    }
                }
            }
        }
    }

    // ---- C write ----
    #pragma unroll
    for (int mt = 0; mt < 2; mt++) {
        #pragma unroll
        for (int r = 0; r < 4; r++) {
            int row = m0 + wm * 32 + mt * 16 + kq * 4 + r;
            if (row < M) {
                #pragma unroll
                for (int nt = 0; nt < 4; nt++) {
                    int col = n0 + wn * 64 + nt * 16 + c16;
                    if (col < N) {
                        float v = acc[mt][nt][r];
                        if (bias) v += bias[col];
                        if (do_relu) v = fmaxf(v, 0.f);
                        size_t idx = (size_t)row * N + col;
                        if (Cf) Cf[idx] = v;
                        if (Chi) {
                            unsigned short hh = f2bf(v);
                            Chi[idx] = hh;
                            if (Clo) Clo[idx] = f2bf(v - bf2f(hh));
                        }
                    }
                }
            }
        }
    }
}

__device__ __forceinline__ float wave_max_f(float v) {
    #pragma unroll
    for (int off = 32; off; off >>= 1) v = fmaxf(v, __shfl_xor(v, off));
    return v;
}
__device__ __forceinline__ float wave_sum_f(float v) {
    #pragma unroll
    for (int off = 32; off; off >>= 1) v += __shfl_xor(v, off);
    return v;
}

// ---------------------------------------------------------------------------
// Aggregation (verified r5): one wave per node, all heads, bf16 gather;
// output written as split hi/lo (exact) for the next GEMM.
// ---------------------------------------------------------------------------
template <int H, bool MEAN_BN>
__global__ __launch_bounds__(256) void agg_k(
    const unsigned short* __restrict__ hfeat,   // [N, H*64] bf16
    const float* __restrict__ a_s, const float* __restrict__ a_d,
    const int* __restrict__ rowptr, const int* __restrict__ csr,
    const float* __restrict__ scale,   // MEAN_BN: folded BN scale; else unused
    const float* __restrict__ shift,   // MEAN_BN: folded BN shift; else bias
    unsigned short* __restrict__ outhi, unsigned short* __restrict__ outlo,
    int N) {
    constexpr int OUT = H * 64;
    constexpr int F = H;
    constexpr int G = 64 / H;
    __shared__ float alpha_s[4][H][65];
    const int wv = threadIdx.x >> 6;
    const int lane = threadIdx.x & 63;
    const int node = blockIdx.x * 4 + wv;
    if (node >= N) return;        // no __syncthreads in this kernel — safe

    const int row = rowptr[node];
    const int deg = rowptr[node + 1] - row;
    const int hl = lane / G;

    float adn[H];
    #pragma unroll
    for (int h = 0; h < H; h++) adn[h] = a_d[(size_t)node * H + h];

    float acc[F] = {};

    if (deg <= 64) {
        int s = 0;
        float e[H];
        #pragma unroll
        for (int h = 0; h < H; h++) e[h] = -INFINITY;
        if (lane < deg) {
            s = csr[row + lane];
            const float* ap = a_s + (size_t)s * H;
            if constexpr (H >= 4) {
                #pragma unroll
                for (int h4 = 0; h4 < H; h4 += 4) {
                    float4 av = *(const float4*)(ap + h4);
                    e[h4 + 0] = av.x + adn[h4 + 0];
                    e[h4 + 1] = av.y + adn[h4 + 1];
                    e[h4 + 2] = av.z + adn[h4 + 2];
                    e[h4 + 3] = av.w + adn[h4 + 3];
                }
            } else {
                e[0] = ap[0] + adn[0];
            }
            #pragma unroll
            for (int h = 0; h < H; h++) e[h] = e[h] > 0.f ? e[h] : 0.2f * e[h];
        }
        float m[H], p[H], inv[H];
        #pragma unroll
        for (int h = 0; h < H; h++) m[h] = wave_max_f(e[h]);
        #pragma unroll
        for (int h = 0; h < H; h++) p[h] = (lane < deg) ? __expf(e[h] - m[h]) : 0.f;
        #pragma unroll
        for (int h = 0; h < H; h++) inv[h] = 1.f / (wave_sum_f(p[h]) + 1e-16f);
        if (lane < deg) {
            #pragma unroll
            for (int h = 0; h < H; h++) alpha_s[wv][h][lane] = p[h] * inv[h];
        }
        asm volatile("s_waitcnt lgkmcnt(0)" ::: "memory");
        for (int jj = 0; jj < deg; jj++) {
            int ss = __builtin_amdgcn_readlane(s, jj);
            float al = alpha_s[wv][hl][jj];
            const unsigned short* rp = hfeat + (size_t)ss * OUT + lane * F;
            if constexpr (F == 8) {
                u16x8_t u = *(const u16x8_t*)rp;
                #pragma unroll
                for (int i = 0; i < 8; i++) acc[i] = fmaf(al, bf2f(u[i]), acc[i]);
            } else if constexpr (F == 4) {
                u16x4_t u = *(const u16x4_t*)rp;
                #pragma unroll
                for (int i = 0; i < 4; i++) acc[i] = fmaf(al, bf2f(u[i]), acc[i]);
            } else {
                acc[0] = fmaf(al, bf2f(rp[0]), acc[0]);
            }
        }
    } else {
        float m[H];
        #pragma unroll
        for (int h = 0; h < H; h++) m[h] = -INFINITY;
        for (int c0 = 0; c0 < deg; c0 += 64) {
            int j = c0 + lane;
            if (j < deg) {
                int s2 = csr[row + j];
                #pragma unroll
                for (int h = 0; h < H; h++) {
                    float e = a_s[(size_t)s2 * H + h] + adn[h];
                    e = e > 0.f ? e : 0.2f * e;
                    m[h] = fmaxf(m[h], e);
                }
            }
        }
        #pragma unroll
        for (int h = 0; h < H; h++) m[h] = wave_max_f(m[h]);
        float dsum[H] = {};
        for (int c0 = 0; c0 < deg; c0 += 64) {
            int j = c0 + lane;
            if (j < deg) {
                int s2 = csr[row + j];
                #pragma unroll
                for (int h = 0; h < H; h++) {
                    float e = a_s[(size_t)s2 * H + h] + adn[h];
                    e = e > 0.f ? e : 0.2f * e;
                    dsum[h] += __expf(e - m[h]);
                }
            }
        }
        float inv[H];
        #pragma unroll
        for (int h = 0; h < H; h++) inv[h] = 1.f / (wave_sum_f(dsum[h]) + 1e-16f);
        for (int c0 = 0; c0 < deg; c0 += 64) {
            int j = c0 + lane;
            int cnt = min(64, deg - c0);
            int s = 0;
            if (j < deg) {
                s = csr[row + j];
                #pragma unroll
                for (int h = 0; h < H; h++) {
                    float e = a_s[(size_t)s * H + h] + adn[h];
                    e = e > 0.f ? e : 0.2f * e;
                    alpha_s[wv][h][lane] = __expf(e - m[h]) * inv[h];
                }
            }
            asm volatile("s_waitcnt lgkmcnt(0)" ::: "memory");
            for (int jj = 0; jj < cnt; jj++) {
                int ss = __builtin_amdgcn_readlane(s, jj);
                float al = alpha_s[wv][hl][jj];
                const unsigned short* rp = hfeat + (size_t)ss * OUT + lane * F;
                if constexpr (F == 8) {
                    u16x8_t u = *(const u16x8_t*)rp;
                    #pragma unroll
                    for (int i = 0; i < 8; i++) acc[i] = fmaf(al, bf2f(u[i]), acc[i]);
                } else if constexpr (F == 4) {
                    u16x4_t u = *(const u16x4_t*)rp;
                    #pragma unroll
                    for (int i = 0; i < 4; i++) acc[i] = fmaf(al, bf2f(u[i]), acc[i]);
                } else {
                    acc[0] = fmaf(al, bf2f(rp[0]), acc[0]);
                }
            }
            asm volatile("s_waitcnt lgkmcnt(0)" ::: "memory");
        }
    }

    if constexpr (MEAN_BN) {
        #pragma unroll
        for (int i = 0; i < F; i++) {
            #pragma unroll
            for (int msk = G; msk < 64; msk <<= 1)
                acc[i] += __shfl_xor(acc[i], msk);
        }
        if (lane < G) {
            int c0 = lane * F;
            #pragma unroll
            for (int i = 0; i < F; i++) {
                float v = fmaf(acc[i] * (1.0f / H), scale[c0 + i], shift[c0 + i]);
                v = fmaxf(v, 0.f);
                unsigned short hh = f2bf(v);
                outhi[(size_t)node * 64 + c0 + i] = hh;
                outlo[(size_t)node * 64 + c0 + i] = f2bf(v - bf2f(hh));
            }
        }
    } else {
        float v = acc[0] + shift[lane];
        unsigned short hh = f2bf(v);
        outhi[(size_t)node * 64 + lane] = hh;
        outlo[(size_t)node * 64 + lane] = f2bf(v - bf2f(hh));
    }
}

// ---------------------------------------------------------------------------
// Softmax over N_CLS logits, wave per node.
// ---------------------------------------------------------------------------
__global__ __launch_bounds__(256) void softmax_k(const float* __restrict__ logits,
                                                 float* __restrict__ out, int N) {
    int lane = threadIdx.x & 63;
    int n = (blockIdx.x * blockDim.x + threadIdx.x) >> 6;
    if (n >= N) return;
    float lg = (lane < N_CLS) ? logits[(size_t)n * N_CLS + lane] : -INFINITY;
    float m = wave_max_f(lg);
    float p = (lane < N_CLS) ? __expf(lg - m) : 0.f;
    float s = wave_sum_f(p);
    if (lane < N_CLS) out[(size_t)n * N_CLS + lane] = p / s;
}

// ---------------------------------------------------------------------------
extern "C" void kernel_launch(void* const* d_in, const int* in_sizes, int n_in,
                              void* d_out, int out_size, void* d_ws, size_t ws_size,
                              hipStream_t stream) {
    const int N = NN, E = EE, E2 = EE + NN;
    const float* x    = (const float*)d_in[0];
    const int*   ei   = (const int*)d_in[1];
    const float* W1   = (const float*)d_in[2];
    const float* as1  = (const float*)d_in[3];
    const float* ad1  = (const float*)d_in[4];
    const float* b1   = (const float*)d_in[5];
    const float* W2   = (const float*)d_in[6];
    const float* as2  = (const float*)d_in[7];
    const float* ad2  = (const float*)d_in[8];
    const float* b2   = (const float*)d_in[9];
    const float* W3   = (const float*)d_in[10];
    const float* as3  = (const float*)d_in[11];
    const float* ad3  = (const float*)d_in[12];
    const float* b3   = (const float*)d_in[13];
    const float* bn1g = (const float*)d_in[14];
    const float* bn1b = (const float*)d_in[15];
    const float* bn1m = (const float*)d_in[16];
    const float* bn1v = (const float*)d_in[17];
    const float* bn2g = (const float*)d_in[18];
    const float* bn2b = (const float*)d_in[19];
    const float* bn2m = (const float*)d_in[20];
    const float* bn2v = (const float*)d_in[21];
    const float* cW1  = (const float*)d_in[22];
    const float* cb1  = (const float*)d_in[23];
    const float* cW2  = (const float*)d_in[24];
    const float* cb2  = (const float*)d_in[25];
    float* out = (float*)d_out;

    char* ws = (char*)d_ws;
    size_t off = 0;
    auto alloc = [&](size_t bytes) {
        void* p = ws + off;
        off = (off + bytes + 255) & ~(size_t)255;
        return p;
    };
    int*   rowptr = (int*)alloc((size_t)(N + 1) * 4);
    int*   cursor = (int*)alloc((size_t)N * 4);
    int*   excl   = (int*)alloc((size_t)N * 4);
    int*   bsum   = (int*)alloc(64 * 4);
    int*   csr    = (int*)alloc((size_t)E2 * 4);
    unsigned short* hbf = (unsigned short*)alloc((size_t)N * 512 * 2);  // bf16 h
    float* asb    = (float*)alloc((size_t)N * 8 * 4);
    float* adb    = (float*)alloc((size_t)N * 8 * 4);
    unsigned short* xhi = (unsigned short*)alloc((size_t)N * D_IN * 2);
    unsigned short* xlo = (unsigned short*)alloc((size_t)N * D_IN * 2);
    unsigned short* f1h = (unsigned short*)alloc((size_t)N * 64 * 2);
    unsigned short* f1l = (unsigned short*)alloc((size_t)N * 64 * 2);
    unsigned short* f2h = (unsigned short*)alloc((size_t)N * 64 * 2);
    unsigned short* f2l = (unsigned short*)alloc((size_t)N * 64 * 2);
    unsigned short* f3h = (unsigned short*)alloc((size_t)N * 64 * 2);
    unsigned short* f3l = (unsigned short*)alloc((size_t)N * 64 * 2);
    unsigned short* zh  = (unsigned short*)alloc((size_t)N * 64 * 2);
    unsigned short* zl  = (unsigned short*)alloc((size_t)N * 64 * 2);
    unsigned short* wthi = (unsigned short*)alloc((size_t)512 * 256 * 2);
    unsigned short* wtlo = (unsigned short*)alloc((size_t)512 * 256 * 2);
    float* sc1 = (float*)alloc(64 * 4);
    float* sh1 = (float*)alloc(64 * 4);
    float* sc2 = (float*)alloc(64 * 4);
    float* sh2 = (float*)alloc(64 * 4);
    float* logits = (float*)alloc((size_t)N * N_CLS * 4);

    const int NB = (N + 1023) / 1024;        // 49 scan blocks

    // ---- CSR build (parallel scan) + BN fold ----
    zero_k<<<(N + 255) / 256, 256, 0, stream>>>(cursor, N);
    count_k<<<(E2 + 255) / 256, 256, 0, stream>>>(ei, cursor, E, N);
    scan1_k<<<NB, 1024, 0, stream>>>(cursor, excl, bsum, N);
    scan2_k<<<1, 64, 0, stream>>>(bsum, NB);
    scan3_k<<<(N + 255) / 256, 256, 0, stream>>>(excl, bsum, rowptr, N, E2);
    zero_k<<<(N + 255) / 256, 256, 0, stream>>>(cursor, N);
    fill_k<<<(E2 + 255) / 256, 256, 0, stream>>>(ei, rowptr, cursor, csr, E, N);
    bnprep_k<<<1, 64, 0, stream>>>(bn1g, bn1b, bn1m, bn1v, b1, sc1, sh1);
    bnprep_k<<<1, 64, 0, stream>>>(bn2g, bn2b, bn2m, bn2v, b2, sc2, sh2);

    const int MB = (N + 63) / 64;
    const int AB = (N + 3) / 4;

    // ---- Layer 1: heads=8, in=256 ----
    cvt_a_k<<<((size_t)N * 256 + 255) / 256, 256, 0, stream>>>(x, xhi, xlo, N * 256);
    cvt_bt_k<<<(256 * 512 + 255) / 256, 256, 0, stream>>>(W1, wthi, wtlo, 256, 512);
    gemm_mfma_k<<<dim3(4, MB), 256, 0, stream>>>(xhi, xlo, wthi, wtlo,
        nullptr, hbf, nullptr, N, 512, 256, nullptr, 0, as1, ad1, asb, adb, 8);
    agg_k<8, true><<<AB, 256, 0, stream>>>(hbf, asb, adb, rowptr, csr, sc1, sh1, f1h, f1l, N);

    // ---- Layer 2: heads=4, in=64 ----
    cvt_bt_k<<<(64 * 256 + 255) / 256, 256, 0, stream>>>(W2, wthi, wtlo, 64, 256);
    gemm_mfma_k<<<dim3(2, MB), 256, 0, stream>>>(f1h, f1l, wthi, wtlo,
        nullptr, hbf, nullptr, N, 256, 64, nullptr, 0, as2, ad2, asb, adb, 4);
    agg_k<4, true><<<AB, 256, 0, stream>>>(hbf, asb, adb, rowptr, csr, sc2, sh2, f2h, f2l, N);

    // ---- Layer 3: heads=1, in=64, concat ----
    cvt_bt_k<<<(64 * 64 + 255) / 256, 256, 0, stream>>>(W3, wthi, wtlo, 64, 64);
    gemm_mfma_k<<<dim3(1, MB), 256, 0, stream>>>(f2h, f2l, wthi, wtlo,
        nullptr, hbf, nullptr, N, 64, 64, nullptr, 0, as3, ad3, asb, adb, 1);
    agg_k<1, false><<<AB, 256, 0, stream>>>(hbf, asb, adb, rowptr, csr, nullptr, b3, f3h, f3l, N);

    // ---- Classifier: z = relu(f3@cW1+cb1) (split out) ; logits ; softmax ----
    cvt_bt_k<<<(64 * 64 + 255) / 256, 256, 0, stream>>>(cW1, wthi, wtlo, 64, 64);
    gemm_mfma_k<<<dim3(1, MB), 256, 0, stream>>>(f3h, f3l, wthi, wtlo,
        nullptr, zh, zl, N, 64, 64, cb1, 1, nullptr, nullptr, nullptr, nullptr, 0);
    cvt_bt_k<<<(64 * N_CLS + 255) / 256, 256, 0, stream>>>(cW2, wthi, wtlo, 64, N_CLS);
    gemm_mfma_k<<<dim3(1, MB), 256, 0, stream>>>(zh, zl, wthi, wtlo,
        logits, nullptr, nullptr, N, N_CLS, 64, cb2, 0, nullptr, nullptr, nullptr, nullptr, 0);
    softmax_k<<<(N + 3) / 4, 256, 0, stream>>>(logits, out, N);
}

// Round 11
// 497.481 us; speedup vs baseline: 1.4484x; 1.0718x over previous
//
#include <hip/hip_runtime.h>
#include <hip/hip_bf16.h>
#include <math.h>

#define NN 50000
#define EE 400000
#define D_IN 256
#define D_H 64
#define N_CLS 50

typedef __attribute__((ext_vector_type(8))) short bfrag;   // 8 bf16 (4 VGPR)
typedef __attribute__((ext_vector_type(4))) float ffrag;   // MFMA C/D
typedef __attribute__((ext_vector_type(8))) unsigned short u16x8_t;
typedef __attribute__((ext_vector_type(4))) unsigned short u16x4_t;

__device__ __forceinline__ unsigned short f2bf(float v) {
    unsigned int u = __float_as_uint(v);
    unsigned int r = (u + 0x7fffu + ((u >> 16) & 1u)) >> 16;   // RNE
    return (unsigned short)r;
}
__device__ __forceinline__ float bf2f(unsigned short b) {
    return __uint_as_float(((unsigned int)b) << 16);
}

// XOR sub-chunk swizzle (r7/r10-verified: 0 bank conflicts). row stride 32
// shorts (64B, unpadded); q = 8-short chunk 0..3. 16B-aligned offsets.
__device__ __forceinline__ int swz(int row, int q) {
    return row * 32 + ((q ^ ((row >> 1) & 3)) << 3);
}

// ---------------------------------------------------------------------------
// CSR construction — parallel 3-phase scan (verified r7)
// ---------------------------------------------------------------------------
__global__ void zero_k(int* p, int n) {
    int i = blockIdx.x * blockDim.x + threadIdx.x;
    if (i < n) p[i] = 0;
}

__global__ void count_k(const int* __restrict__ ei, int* __restrict__ cnt, int E, int N) {
    int i = blockIdx.x * blockDim.x + threadIdx.x;
    if (i >= E + N) return;
    int dst = (i < E) ? ei[E + i] : (i - E);
    atomicAdd(&cnt[dst], 1);
}

__global__ __launch_bounds__(1024) void scan1_k(const int* __restrict__ counts,
                                                int* __restrict__ excl,
                                                int* __restrict__ bsum, int n) {
    __shared__ int wsum[16];
    int t = threadIdx.x;
    int lane = t & 63, wid = t >> 6;
    int idx = blockIdx.x * 1024 + t;
    int v = (idx < n) ? counts[idx] : 0;
    int incl = v;
    #pragma unroll
    for (int off = 1; off < 64; off <<= 1) {
        int x = __shfl_up(incl, off);
        if (lane >= off) incl += x;
    }
    if (lane == 63) wsum[wid] = incl;
    __syncthreads();
    if (wid == 0) {
        int ws = (lane < 16) ? wsum[lane] : 0;
        int wincl = ws;
        #pragma unroll
        for (int off = 1; off < 16; off <<= 1) {
            int x = __shfl_up(wincl, off);
            if (lane >= off) wincl += x;
        }
        if (lane < 16) wsum[lane] = wincl - ws;   // exclusive wave prefix
    }
    __syncthreads();
    if (idx < n) excl[idx] = wsum[wid] + (incl - v);
    if (t == 1023) bsum[blockIdx.x] = wsum[15] + incl;
}

__global__ void scan2_k(int* __restrict__ bsum, int nb) {
    int lane = threadIdx.x & 63;
    int v = (lane < nb) ? bsum[lane] : 0;
    int incl = v;
    #pragma unroll
    for (int off = 1; off < 64; off <<= 1) {
        int x = __shfl_up(incl, off);
        if (lane >= off) incl += x;
    }
    if (lane < nb) bsum[lane] = incl - v;
}

__global__ void scan3_k(const int* __restrict__ excl, const int* __restrict__ bsum,
                        int* __restrict__ rowptr, int n, int total) {
    int i = blockIdx.x * 256 + threadIdx.x;
    if (i < n) rowptr[i] = excl[i] + bsum[i >> 10];
    if (i == 0) rowptr[n] = total;
}

__global__ void fill_k(const int* __restrict__ ei, const int* __restrict__ rowptr,
                       int* __restrict__ cursor, int* __restrict__ csr, int E, int N) {
    int i = blockIdx.x * blockDim.x + threadIdx.x;
    if (i >= E + N) return;
    int s, d;
    if (i < E) { s = ei[i]; d = ei[E + i]; }
    else       { s = i - E; d = i - E; }
    int pos = atomicAdd(&cursor[d], 1);
    csr[rowptr[d] + pos] = s;
}

// ---------------------------------------------------------------------------
// Split-bf16 conversion kernels (x and weights)
// ---------------------------------------------------------------------------
__global__ void cvt_a_k(const float* __restrict__ a, unsigned short* __restrict__ hi,
                        unsigned short* __restrict__ lo, int n) {
    int i = blockIdx.x * 256 + threadIdx.x;
    if (i >= n) return;
    float v = a[i];
    unsigned short h = f2bf(v);
    hi[i] = h;
    lo[i] = f2bf(v - bf2f(h));
}

__global__ void cvt_bt_k(const float* __restrict__ Bsrc, unsigned short* __restrict__ hi,
                         unsigned short* __restrict__ lo, int K, int N) {
    int i = blockIdx.x * 256 + threadIdx.x;
    if (i >= K * N) return;
    int k = i / N, n = i % N;
    float v = Bsrc[i];
    unsigned short h = f2bf(v);
    hi[(size_t)n * K + k] = h;
    lo[(size_t)n * K + k] = f2bf(v - bf2f(h));
}

// BN folding: scale = g*rsqrt(v+eps); shift = (bias - m)*scale + b
__global__ void bnprep_k(const float* __restrict__ g, const float* __restrict__ b,
                         const float* __restrict__ m, const float* __restrict__ v,
                         const float* __restrict__ bias,
                         float* __restrict__ scale, float* __restrict__ shift) {
    int t = threadIdx.x;
    if (t < 64) {
        float sc = g[t] * rsqrtf(v[t] + 1e-5f);
        scale[t] = sc;
        shift[t] = (bias[t] - m[t]) * sc + b[t];
    }
}

// ---------------------------------------------------------------------------
// Split-bf16 MFMA GEMM (r10-verified: r5 structure + conflict-free XOR LDS).
// 64x128 tile, BK=32, 4 waves 2x2, wave tile 32x64 = 2x4 MFMAs x 3 split
// products. Fused epilogues: fp32/bf16(+lo) C, bias+ReLU, attention scores.
// ---------------------------------------------------------------------------
__global__ __launch_bounds__(256) void gemm_mfma_k(
    const unsigned short* __restrict__ Ahi, const unsigned short* __restrict__ Alo,
    const unsigned short* __restrict__ BThi, const unsigned short* __restrict__ BTlo,
    float* __restrict__ Cf, unsigned short* __restrict__ Chi, unsigned short* __restrict__ Clo,
    int M, int N, int K,
    const float* __restrict__ bias, int do_relu,
    const float* __restrict__ att_s, const float* __restrict__ att_d,
    float* __restrict__ asb, float* __restrict__ adb, int H) {
    __shared__ unsigned short sAh[64 * 32];
    __shared__ unsigned short sAl[64 * 32];
    __shared__ unsigned short sBh[128 * 32];
    __shared__ unsigned short sBl[128 * 32];
    const int tid = threadIdx.x;
    const int m0 = blockIdx.y * 64;
    const int n0 = blockIdx.x * 128;
    const int lane = tid & 63, w = tid >> 6;
    const int wm = w >> 1, wn = w & 1;
    const int c16 = lane & 15, kq = lane >> 4;
    const int arow = tid >> 2;          // 0..63
    const int q    = tid & 3;           // 8-short chunk 0..3
    const int akc  = q * 8;
    const int aM  = min(m0 + arow, M - 1);
    const int bn0 = min(n0 + arow, N - 1);
    const int bn1 = min(n0 + 64 + arow, N - 1);
    const int wA  = swz(arow, q);
    const int wB0 = swz(arow, q);
    const int wB1 = swz(64 + arow, q);
    ffrag acc[2][4] = {};

    for (int k0 = 0; k0 < K; k0 += 32) {
        bfrag va_h  = *(const bfrag*)(Ahi  + (size_t)aM  * K + k0 + akc);
        bfrag va_l  = *(const bfrag*)(Alo  + (size_t)aM  * K + k0 + akc);
        bfrag vb_h0 = *(const bfrag*)(BThi + (size_t)bn0 * K + k0 + akc);
        bfrag vb_l0 = *(const bfrag*)(BTlo + (size_t)bn0 * K + k0 + akc);
        bfrag vb_h1 = *(const bfrag*)(BThi + (size_t)bn1 * K + k0 + akc);
        bfrag vb_l1 = *(const bfrag*)(BTlo + (size_t)bn1 * K + k0 + akc);
        __syncthreads();
        *(bfrag*)&sAh[wA]  = va_h;
        *(bfrag*)&sAl[wA]  = va_l;
        *(bfrag*)&sBh[wB0] = vb_h0;
        *(bfrag*)&sBl[wB0] = vb_l0;
        *(bfrag*)&sBh[wB1] = vb_h1;
        *(bfrag*)&sBl[wB1] = vb_l1;
        __syncthreads();
        bfrag ah[2], al_[2], bh[4], bl[4];
        #pragma unroll
        for (int mt = 0; mt < 2; mt++) {
            int ra = wm * 32 + mt * 16 + c16;
            ah[mt]  = *(const bfrag*)&sAh[swz(ra, kq)];
            al_[mt] = *(const bfrag*)&sAl[swz(ra, kq)];
        }
        #pragma unroll
        for (int nt = 0; nt < 4; nt++) {
            int rb = wn * 64 + nt * 16 + c16;
            bh[nt] = *(const bfrag*)&sBh[swz(rb, kq)];
            bl[nt] = *(const bfrag*)&sBl[swz(rb, kq)];
        }
        #pragma unroll
        for (int mt = 0; mt < 2; mt++)
            #pragma unroll
            for (int nt = 0; nt < 4; nt++) {
                acc[mt][nt] = __builtin_amdgcn_mfma_f32_16x16x32_bf16(ah[mt],  bh[nt], acc[mt][nt], 0, 0, 0);
                acc[mt][nt] = __builtin_amdgcn_mfma_f32_16x16x32_bf16(ah[mt],  bl[nt], acc[mt][nt], 0, 0, 0);
                acc[mt][nt] = __builtin_amdgcn_mfma_f32_16x16x32_bf16(al_[mt], bh[nt], acc[mt][nt], 0, 0, 0);
            }
    }

    // ---- fused attention scores (raw h, pre-bias/relu; GAT layers only) ----
    if (att_s) {
        int hidx = n0 / 64 + wn;
        if (hidx < H) {
            float s_att[4], d_att[4];
            #pragma unroll
            for (int nt = 0; nt < 4; nt++) {
                s_att[nt] = att_s[hidx * 64 + nt * 16 + c16];
                d_att[nt] = att_d[hidx * 64 + nt * 16 + c16];
            }
            #pragma unroll
            for (int mt = 0; mt < 2; mt++) {
                #pragma unroll
                for (int r = 0; r < 4; r++) {
                    int row = m0 + wm * 32 + mt * 16 + kq * 4 + r;
                    float ps = 0.f, pd = 0.f;
                    #pragma unroll
                    for (int nt = 0; nt < 4; nt++) {
                        ps = fmaf(acc[mt][nt][r], s_att[nt], ps);
                        pd = fmaf(acc[mt][nt][r], d_att[nt], pd);
                    }
                    #pragma unroll
                    for (int msk = 1; msk < 16; msk <<= 1) {
                        ps += __shfl_xor(ps, msk);
                        pd += __shfl_xor(pd, msk);
                    }
                    if (c16 == 0 && row < M) {
                        asb[(size_t)row * H + hidx] = ps;
                        adb[(size_t)row * H + hidx] = pd;
                    }
                }
            }
        }
    }

    // ---- C write ----
    #pragma unroll
    for (int mt = 0; mt < 2; mt++) {
        #pragma unroll
        for (int r = 0; r < 4; r++) {
            int row = m0 + wm * 32 + mt * 16 + kq * 4 + r;
            if (row < M) {
                #pragma unroll
                for (int nt = 0; nt < 4; nt++) {
                    int col = n0 + wn * 64 + nt * 16 + c16;
                    if (col < N) {
                        float v = acc[mt][nt][r];
                        if (bias) v += bias[col];
                        if (do_relu) v = fmaxf(v, 0.f);
                        size_t idx = (size_t)row * N + col;
                        if (Cf) Cf[idx] = v;
                        if (Chi) {
                            unsigned short hh = f2bf(v);
                            Chi[idx] = hh;
                            if (Clo) Clo[idx] = f2bf(v - bf2f(hh));
                        }
                    }
                }
            }
        }
    }
}

__device__ __forceinline__ float wave_max_f(float v) {
    #pragma unroll
    for (int off = 32; off; off >>= 1) v = fmaxf(v, __shfl_xor(v, off));
    return v;
}
__device__ __forceinline__ float wave_sum_f(float v) {
    #pragma unroll
    for (int off = 32; off; off >>= 1) v += __shfl_xor(v, off);
    return v;
}

// ---------------------------------------------------------------------------
// Aggregation: one wave per node, all heads, bf16 gather (r10 structure).
// NEW softmax phase: lane = (edge-in-chunk, head) pair — one exp per lane,
// stride-H butterfly for denom, normalization deferred to one epilogue mult
// (denom constant per (node,head): sum(p*h)/denom == sum((p/denom)*h)).
// Rare deg>64 path keeps the old max-based code (inv=1).
// ---------------------------------------------------------------------------
template <int H, bool MEAN_BN>
__global__ __launch_bounds__(256) void agg_k(
    const unsigned short* __restrict__ hfeat,   // [N, H*64] bf16
    const float* __restrict__ a_s, const float* __restrict__ a_d,
    const int* __restrict__ rowptr, const int* __restrict__ csr,
    const float* __restrict__ scale,   // MEAN_BN: folded BN scale; else unused
    const float* __restrict__ shift,   // MEAN_BN: folded BN shift; else bias
    unsigned short* __restrict__ outhi, unsigned short* __restrict__ outlo,
    int N) {
    constexpr int OUT = H * 64;
    constexpr int F = H;          // channels per lane (gather phase)
    constexpr int G = 64 / H;     // lanes per head (gather phase)
    constexpr int EPC = 64 / H;   // edges per chunk (softmax phase)
    __shared__ float alpha_s[4][H][65];
    __shared__ int srcb[4][64];
    const int wv = threadIdx.x >> 6;
    const int lane = threadIdx.x & 63;
    const int node = blockIdx.x * 4 + wv;
    if (node >= N) return;        // no __syncthreads in this kernel — safe

    const int row = rowptr[node];
    const int deg = rowptr[node + 1] - row;
    const int hl = lane / G;      // gather-phase head of this lane

    float acc[F] = {};
    float inv = 1.f;

    if (deg <= 64) {
        // ---- softmax phase: lane = (j, h); one exp per lane ----
        const int j8 = lane / H;
        const int h8 = lane % H;
        float adn_own = a_d[(size_t)node * H + h8];
        float psum = 0.f;
        for (int c0 = 0; c0 < deg; c0 += EPC) {
            int jj = c0 + j8;
            if (jj < deg) {
                int s = csr[row + jj];
                if (h8 == 0) srcb[wv][jj] = s;
                float e = a_s[(size_t)s * H + h8] + adn_own;
                e = e > 0.f ? e : 0.2f * e;
                float p = __expf(e);
                alpha_s[wv][h8][jj] = p;
                psum += p;
            }
        }
        #pragma unroll
        for (int msk = H; msk < 64; msk <<= 1)
            psum += __shfl_xor(psum, msk);
        float invd = 1.f / (psum + 1e-16f);      // lane L holds denom of head L%H
        inv = __shfl(invd, hl);                  // lane 'hl' has h8 == hl
        asm volatile("s_waitcnt lgkmcnt(0)" ::: "memory");
        // ---- gather phase ----
        for (int jj = 0; jj < deg; jj++) {
            int ss = srcb[wv][jj];
            float al = alpha_s[wv][hl][jj];
            const unsigned short* rp = hfeat + (size_t)ss * OUT + lane * F;
            if constexpr (F == 8) {
                u16x8_t u = *(const u16x8_t*)rp;
                #pragma unroll
                for (int i = 0; i < 8; i++) acc[i] = fmaf(al, bf2f(u[i]), acc[i]);
            } else if constexpr (F == 4) {
                u16x4_t u = *(const u16x4_t*)rp;
                #pragma unroll
                for (int i = 0; i < 4; i++) acc[i] = fmaf(al, bf2f(u[i]), acc[i]);
            } else {
                acc[0] = fmaf(al, bf2f(rp[0]), acc[0]);
            }
        }
    } else {
        // ---- general path (deg > 64; essentially never for this graph) ----
        float adn[H];
        #pragma unroll
        for (int h = 0; h < H; h++) adn[h] = a_d[(size_t)node * H + h];
        float m[H];
        #pragma unroll
        for (int h = 0; h < H; h++) m[h] = -INFINITY;
        for (int c0 = 0; c0 < deg; c0 += 64) {
            int j = c0 + lane;
            if (j < deg) {
                int s2 = csr[row + j];
                #pragma unroll
                for (int h = 0; h < H; h++) {
                    float e = a_s[(size_t)s2 * H + h] + adn[h];
                    e = e > 0.f ? e : 0.2f * e;
                    m[h] = fmaxf(m[h], e);
                }
            }
        }
        #pragma unroll
        for (int h = 0; h < H; h++) m[h] = wave_max_f(m[h]);
        float dsum[H] = {};
        for (int c0 = 0; c0 < deg; c0 += 64) {
            int j = c0 + lane;
            if (j < deg) {
                int s2 = csr[row + j];
                #pragma unroll
                for (int h = 0; h < H; h++) {
                    float e = a_s[(size_t)s2 * H + h] + adn[h];
                    e = e > 0.f ? e : 0.2f * e;
                    dsum[h] += __expf(e - m[h]);
                }
            }
        }
        float dinv[H];
        #pragma unroll
        for (int h = 0; h < H; h++) dinv[h] = 1.f / (wave_sum_f(dsum[h]) + 1e-16f);
        for (int c0 = 0; c0 < deg; c0 += 64) {
            int j = c0 + lane;
            int cnt = min(64, deg - c0);
            int s = 0;
            if (j < deg) {
                s = csr[row + j];
                #pragma unroll
                for (int h = 0; h < H; h++) {
                    float e = a_s[(size_t)s * H + h] + adn[h];
                    e = e > 0.f ? e : 0.2f * e;
                    alpha_s[wv][h][lane] = __expf(e - m[h]) * dinv[h];
                }
            }
            asm volatile("s_waitcnt lgkmcnt(0)" ::: "memory");
            for (int jj = 0; jj < cnt; jj++) {
                int ss = __builtin_amdgcn_readlane(s, jj);
                float al = alpha_s[wv][hl][jj];
                const unsigned short* rp = hfeat + (size_t)ss * OUT + lane * F;
                if constexpr (F == 8) {
                    u16x8_t u = *(const u16x8_t*)rp;
                    #pragma unroll
                    for (int i = 0; i < 8; i++) acc[i] = fmaf(al, bf2f(u[i]), acc[i]);
                } else if constexpr (F == 4) {
                    u16x4_t u = *(const u16x4_t*)rp;
                    #pragma unroll
                    for (int i = 0; i < 4; i++) acc[i] = fmaf(al, bf2f(u[i]), acc[i]);
                } else {
                    acc[0] = fmaf(al, bf2f(rp[0]), acc[0]);
                }
            }
            asm volatile("s_waitcnt lgkmcnt(0)" ::: "memory");
        }
        inv = 1.f;   // alpha already normalized in this path
    }

    // ---- epilogue: deferred normalization, head-mean, BN, split write ----
    #pragma unroll
    for (int i = 0; i < F; i++) acc[i] *= inv;

    if constexpr (MEAN_BN) {
        #pragma unroll
        for (int i = 0; i < F; i++) {
            #pragma unroll
            for (int msk = G; msk < 64; msk <<= 1)
                acc[i] += __shfl_xor(acc[i], msk);
        }
        if (lane < G) {
            int c0 = lane * F;
            #pragma unroll
            for (int i = 0; i < F; i++) {
                float v = fmaf(acc[i] * (1.0f / H), scale[c0 + i], shift[c0 + i]);
                v = fmaxf(v, 0.f);
                unsigned short hh = f2bf(v);
                outhi[(size_t)node * 64 + c0 + i] = hh;
                outlo[(size_t)node * 64 + c0 + i] = f2bf(v - bf2f(hh));
            }
        }
    } else {
        float v = acc[0] + shift[lane];
        unsigned short hh = f2bf(v);
        outhi[(size_t)node * 64 + lane] = hh;
        outlo[(size_t)node * 64 + lane] = f2bf(v - bf2f(hh));
    }
}

// ---------------------------------------------------------------------------
// Softmax over N_CLS logits, wave per node.
// ---------------------------------------------------------------------------
__global__ __launch_bounds__(256) void softmax_k(const float* __restrict__ logits,
                                                 float* __restrict__ out, int N) {
    int lane = threadIdx.x & 63;
    int n = (blockIdx.x * blockDim.x + threadIdx.x) >> 6;
    if (n >= N) return;
    float lg = (lane < N_CLS) ? logits[(size_t)n * N_CLS + lane] : -INFINITY;
    float m = wave_max_f(lg);
    float p = (lane < N_CLS) ? __expf(lg - m) : 0.f;
    float s = wave_sum_f(p);
    if (lane < N_CLS) out[(size_t)n * N_CLS + lane] = p / s;
}

// ---------------------------------------------------------------------------
extern "C" void kernel_launch(void* const* d_in, const int* in_sizes, int n_in,
                              void* d_out, int out_size, void* d_ws, size_t ws_size,
                              hipStream_t stream) {
    const int N = NN, E = EE, E2 = EE + NN;
    const float* x    = (const float*)d_in[0];
    const int*   ei   = (const int*)d_in[1];
    const float* W1   = (const float*)d_in[2];
    const float* as1  = (const float*)d_in[3];
    const float* ad1  = (const float*)d_in[4];
    const float* b1   = (const float*)d_in[5];
    const float* W2   = (const float*)d_in[6];
    const float* as2  = (const float*)d_in[7];
    const float* ad2  = (const float*)d_in[8];
    const float* b2   = (const float*)d_in[9];
    const float* W3   = (const float*)d_in[10];
    const float* as3  = (const float*)d_in[11];
    const float* ad3  = (const float*)d_in[12];
    const float* b3   = (const float*)d_in[13];
    const float* bn1g = (const float*)d_in[14];
    const float* bn1b = (const float*)d_in[15];
    const float* bn1m = (const float*)d_in[16];
    const float* bn1v = (const float*)d_in[17];
    const float* bn2g = (const float*)d_in[18];
    const float* bn2b = (const float*)d_in[19];
    const float* bn2m = (const float*)d_in[20];
    const float* bn2v = (const float*)d_in[21];
    const float* cW1  = (const float*)d_in[22];
    const float* cb1  = (const float*)d_in[23];
    const float* cW2  = (const float*)d_in[24];
    const float* cb2  = (const float*)d_in[25];
    float* out = (float*)d_out;

    char* ws = (char*)d_ws;
    size_t off = 0;
    auto alloc = [&](size_t bytes) {
        void* p = ws + off;
        off = (off + bytes + 255) & ~(size_t)255;
        return p;
    };
    int*   rowptr = (int*)alloc((size_t)(N + 1) * 4);
    int*   cursor = (int*)alloc((size_t)N * 4);
    int*   excl   = (int*)alloc((size_t)N * 4);
    int*   bsum   = (int*)alloc(64 * 4);
    int*   csr    = (int*)alloc((size_t)E2 * 4);
    unsigned short* hbf = (unsigned short*)alloc((size_t)N * 512 * 2);  // bf16 h
    float* asb    = (float*)alloc((size_t)N * 8 * 4);
    float* adb    = (float*)alloc((size_t)N * 8 * 4);
    unsigned short* xhi = (unsigned short*)alloc((size_t)N * D_IN * 2);
    unsigned short* xlo = (unsigned short*)alloc((size_t)N * D_IN * 2);
    unsigned short* f1h = (unsigned short*)alloc((size_t)N * 64 * 2);
    unsigned short* f1l = (unsigned short*)alloc((size_t)N * 64 * 2);
    unsigned short* f2h = (unsigned short*)alloc((size_t)N * 64 * 2);
    unsigned short* f2l = (unsigned short*)alloc((size_t)N * 64 * 2);
    unsigned short* f3h = (unsigned short*)alloc((size_t)N * 64 * 2);
    unsigned short* f3l = (unsigned short*)alloc((size_t)N * 64 * 2);
    unsigned short* zh  = (unsigned short*)alloc((size_t)N * 64 * 2);
    unsigned short* zl  = (unsigned short*)alloc((size_t)N * 64 * 2);
    unsigned short* wthi = (unsigned short*)alloc((size_t)512 * 256 * 2);
    unsigned short* wtlo = (unsigned short*)alloc((size_t)512 * 256 * 2);
    float* sc1 = (float*)alloc(64 * 4);
    float* sh1 = (float*)alloc(64 * 4);
    float* sc2 = (float*)alloc(64 * 4);
    float* sh2 = (float*)alloc(64 * 4);
    float* logits = (float*)alloc((size_t)N * N_CLS * 4);

    const int NB = (N + 1023) / 1024;        // 49 scan blocks

    // ---- CSR build (parallel scan) + BN fold ----
    zero_k<<<(N + 255) / 256, 256, 0, stream>>>(cursor, N);
    count_k<<<(E2 + 255) / 256, 256, 0, stream>>>(ei, cursor, E, N);
    scan1_k<<<NB, 1024, 0, stream>>>(cursor, excl, bsum, N);
    scan2_k<<<1, 64, 0, stream>>>(bsum, NB);
    scan3_k<<<(N + 255) / 256, 256, 0, stream>>>(excl, bsum, rowptr, N, E2);
    zero_k<<<(N + 255) / 256, 256, 0, stream>>>(cursor, N);
    fill_k<<<(E2 + 255) / 256, 256, 0, stream>>>(ei, rowptr, cursor, csr, E, N);
    bnprep_k<<<1, 64, 0, stream>>>(bn1g, bn1b, bn1m, bn1v, b1, sc1, sh1);
    bnprep_k<<<1, 64, 0, stream>>>(bn2g, bn2b, bn2m, bn2v, b2, sc2, sh2);

    const int MB = (N + 63) / 64;
    const int AB = (N + 3) / 4;

    // ---- Layer 1: heads=8, in=256 ----
    cvt_a_k<<<((size_t)N * 256 + 255) / 256, 256, 0, stream>>>(x, xhi, xlo, N * 256);
    cvt_bt_k<<<(256 * 512 + 255) / 256, 256, 0, stream>>>(W1, wthi, wtlo, 256, 512);
    gemm_mfma_k<<<dim3(4, MB), 256, 0, stream>>>(xhi, xlo, wthi, wtlo,
        nullptr, hbf, nullptr, N, 512, 256, nullptr, 0, as1, ad1, asb, adb, 8);
    agg_k<8, true><<<AB, 256, 0, stream>>>(hbf, asb, adb, rowptr, csr, sc1, sh1, f1h, f1l, N);

    // ---- Layer 2: heads=4, in=64 ----
    cvt_bt_k<<<(64 * 256 + 255) / 256, 256, 0, stream>>>(W2, wthi, wtlo, 64, 256);
    gemm_mfma_k<<<dim3(2, MB), 256, 0, stream>>>(f1h, f1l, wthi, wtlo,
        nullptr, hbf, nullptr, N, 256, 64, nullptr, 0, as2, ad2, asb, adb, 4);
    agg_k<4, true><<<AB, 256, 0, stream>>>(hbf, asb, adb, rowptr, csr, sc2, sh2, f2h, f2l, N);

    // ---- Layer 3: heads=1, in=64, concat ----
    cvt_bt_k<<<(64 * 64 + 255) / 256, 256, 0, stream>>>(W3, wthi, wtlo, 64, 64);
    gemm_mfma_k<<<dim3(1, MB), 256, 0, stream>>>(f2h, f2l, wthi, wtlo,
        nullptr, hbf, nullptr, N, 64, 64, nullptr, 0, as3, ad3, asb, adb, 1);
    agg_k<1, false><<<AB, 256, 0, stream>>>(hbf, asb, adb, rowptr, csr, nullptr, b3, f3h, f3l, N);

    // ---- Classifier: z = relu(f3@cW1+cb1) (split out) ; logits ; softmax ----
    cvt_bt_k<<<(64 * 64 + 255) / 256, 256, 0, stream>>>(cW1, wthi, wtlo, 64, 64);
    gemm_mfma_k<<<dim3(1, MB), 256, 0, stream>>>(f3h, f3l, wthi, wtlo,
        nullptr, zh, zl, N, 64, 64, cb1, 1, nullptr, nullptr, nullptr, nullptr, 0);
    cvt_bt_k<<<(64 * N_CLS + 255) / 256, 256, 0, stream>>>(cW2, wthi, wtlo, 64, N_CLS);
    gemm_mfma_k<<<dim3(1, MB), 256, 0, stream>>>(zh, zl, wthi, wtlo,
        logits, nullptr, nullptr, N, N_CLS, 64, cb2, 0, nullptr, nullptr, nullptr, nullptr, 0);
    softmax_k<<<(N + 3) / 4, 256, 0, stream>>>(logits, out, N);
}